// Round 11
// baseline (331.463 us; speedup 1.0000x reference)
//
#include <hip/hip_runtime.h>

#define NN 100000
#define NE 1600000
#define NB 391              // ceil(NN/256) node-buckets of 256 dst nodes
#define NBP 512             // padded bucket count (pow2 for scans)
#define CHUNK 8192
#define NCHUNK 196          // ceil(NE/CHUNK); 196*8192 >= NE

static __device__ __forceinline__ unsigned short f2bf(float f) {
    unsigned u = __float_as_uint(f);
    u += 0x7fffu + ((u >> 16) & 1u);   // RNE
    return (unsigned short)(u >> 16);
}

// ---- KA: per-chunk bucket histogram rows (block-owned: no zeroing, no global atomics) ----
__global__ __launch_bounds__(256) void hist_rows(const int* __restrict__ dst,
                                                 int* __restrict__ C) {
    __shared__ int h[NBP];
    int t = threadIdx.x;
    h[t] = 0; h[t + 256] = 0;
    __syncthreads();
    int base = blockIdx.x * CHUNK;
    int end = min(base + CHUNK, NE);
    for (int e = base + t; e < end; e += 256) atomicAdd(&h[dst[e] >> 8], 1);
    __syncthreads();
    C[blockIdx.x * NBP + t] = h[t];
    C[blockIdx.x * NBP + t + 256] = h[t + 256];
}

// ---- KB: fused scan+place. Each block redundantly reads C (coalesced rows),
// computes bucket totals + its own chunk-prefix, LDS-scans bucket bases, and
// scatters its chunk into exclusive regions. No global atomics; deterministic.
__global__ __launch_bounds__(256) void place_scan(const int* __restrict__ src,
                                                  const int* __restrict__ dst,
                                                  const int* __restrict__ C,
                                                  int* __restrict__ bbase,
                                                  int* __restrict__ pairs) {
    __shared__ int sA[NBP];
    __shared__ int buf[2][256];
    __shared__ int lnext[NBP];
    int t = threadIdx.x;
    int blk = blockIdx.x;
    int tot0 = 0, tot1 = 0, pre0 = 0, pre1 = 0;
    #pragma unroll 4
    for (int c = 0; c < NCHUNK; ++c) {
        int v0 = C[c * NBP + t];
        int v1 = C[c * NBP + t + 256];
        tot0 += v0; tot1 += v1;
        if (c < blk) { pre0 += v0; pre1 += v1; }
    }
    sA[t] = tot0; sA[t + 256] = tot1;
    __syncthreads();
    int a0 = sA[2 * t], a1 = sA[2 * t + 1];
    int ps = a0 + a1;
    int pi = 0;
    buf[0][t] = ps;
    __syncthreads();
    for (int off = 1; off < 256; off <<= 1) {
        int add = (t >= off) ? buf[pi][t - off] : 0;
        buf[1 - pi][t] = buf[pi][t] + add;
        pi ^= 1;
        __syncthreads();
    }
    int incl = buf[pi][t];
    int ex2t = incl - ps;
    sA[2 * t]     = ex2t;        // exclusive bucket base, element 2t
    sA[2 * t + 1] = ex2t + a0;   // element 2t+1
    __syncthreads();
    int ex0 = sA[t], ex1 = sA[t + 256];
    if (blk == 0) {
        bbase[t] = ex0; bbase[t + 256] = ex1;
        if (t == 255) bbase[NBP] = NE;
    }
    lnext[t]       = ex0 + pre0;   // this chunk's exclusive region start
    lnext[t + 256] = ex1 + pre1;
    __syncthreads();
    int base = blk * CHUNK;
    int end = min(base + CHUNK, NE);
    for (int e = base + t; e < end; e += 256) {
        int d = dst[e];
        int p = atomicAdd(&lnext[d >> 8], 1);
        pairs[p] = src[e] | ((d & 255) << 17);
    }
}

// ---- KC: per-bucket CSR build + dinv ----
__global__ __launch_bounds__(256) void bkt_csr(const int* __restrict__ pairs,
                                               const int* __restrict__ base,
                                               int* __restrict__ next,
                                               float* __restrict__ dinv,
                                               int* __restrict__ esrc) {
    __shared__ int cnt[256];
    __shared__ int sbuf[2][256];
    __shared__ int nxt[256];
    int b = blockIdx.x;
    int e0 = base[b], e1 = base[b + 1];
    int t = threadIdx.x;
    cnt[t] = 0;
    __syncthreads();
    for (int i = e0 + t; i < e1; i += 256) atomicAdd(&cnt[pairs[i] >> 17], 1);
    __syncthreads();
    int v = cnt[t];
    int pi = 0; sbuf[0][t] = v; __syncthreads();
    for (int off = 1; off < 256; off <<= 1) {
        int add = (t >= off) ? sbuf[pi][t - off] : 0;
        sbuf[1 - pi][t] = sbuf[pi][t] + add;
        pi ^= 1;
        __syncthreads();
    }
    int incl = sbuf[pi][t];
    int node = b * 256 + t;
    if (node < NN) {
        next[node] = e0 + incl;
        dinv[node] = rsqrtf((float)v + 1.0f);
    }
    nxt[t] = e0 + incl - v;
    __syncthreads();
    for (int i = e0 + t; i < e1; i += 256) {
        int w = pairs[i];
        int p = atomicAdd(&nxt[w >> 17], 1);
        esrc[p] = w & 0x1FFFF;
    }
}

// ---- GEMM [n,64]@[64,64] -> bf16 g = acc*dinv ----
__global__ __launch_bounds__(256) void gemm64g(const float* __restrict__ X,
                                               const float* __restrict__ W,
                                               const float* __restrict__ dinv,
                                               ushort4* __restrict__ G, int n) {
    __shared__ float4 Ws[64][16];
    __shared__ float  Xs[16][68];
    int tid = threadIdx.x;
    const float4* W4 = (const float4*)W;
    #pragma unroll
    for (int i = tid; i < 64 * 16; i += 256) Ws[i >> 4][i & 15] = W4[i];
    {
        int rr = tid >> 4, q = tid & 15;
        int node = blockIdx.x * 16 + rr;
        float4 v = ((const float4*)(X + (size_t)node * 64))[q];
        *(float4*)&Xs[rr][q * 4] = v;
    }
    __syncthreads();
    int r = tid >> 4, cq = tid & 15;
    float4 acc = {0.f, 0.f, 0.f, 0.f};
    #pragma unroll
    for (int k = 0; k < 64; ++k) {
        float x  = Xs[r][k];
        float4 w = Ws[k][cq];
        acc.x += x * w.x; acc.y += x * w.y; acc.z += x * w.z; acc.w += x * w.w;
    }
    int node = blockIdx.x * 16 + r;
    float dd = dinv[node];
    ushort4 pk;
    pk.x = f2bf(acc.x * dd); pk.y = f2bf(acc.y * dd);
    pk.z = f2bf(acc.z * dd); pk.w = f2bf(acc.w * dd);
    G[(size_t)node * 16 + cq] = pk;
}

// ---- gather (bf16): agg + self + bias + relu -> fp32 ----
// one independent wave per dst node — no cross-wave barriers
__global__ __launch_bounds__(256) void gather_bf16(
        const int* __restrict__ next, const int* __restrict__ esrc,
        const float* __restrict__ dinv, const unsigned* __restrict__ G,
        const float* __restrict__ b, float* __restrict__ outH, int n) {
    int node = (int)((blockIdx.x * blockDim.x + threadIdx.x) >> 6);
    if (node >= n) return;
    int lane = threadIdx.x & 63;
    int half = lane >> 5, m = lane & 31;
    int j0 = node ? next[node - 1] : 0;
    int e1 = next[node];
    float ax = 0.f, ay = 0.f;
    int j = j0 + half;
    for (; j + 6 < e1; j += 8) {
        int s0 = esrc[j], s1 = esrc[j + 2], s2 = esrc[j + 4], s3 = esrc[j + 6];
        unsigned u0 = G[s0 * 32 + m];
        unsigned u1 = G[s1 * 32 + m];
        unsigned u2 = G[s2 * 32 + m];
        unsigned u3 = G[s3 * 32 + m];
        ax += __uint_as_float(u0 << 16) + __uint_as_float(u1 << 16)
            + __uint_as_float(u2 << 16) + __uint_as_float(u3 << 16);
        ay += __uint_as_float(u0 & 0xffff0000u) + __uint_as_float(u1 & 0xffff0000u)
            + __uint_as_float(u2 & 0xffff0000u) + __uint_as_float(u3 & 0xffff0000u);
    }
    for (; j < e1; j += 2) {
        unsigned u = G[esrc[j] * 32 + m];
        ax += __uint_as_float(u << 16);
        ay += __uint_as_float(u & 0xffff0000u);
    }
    ax += __shfl_xor(ax, 32);
    ay += __shfl_xor(ay, 32);
    if (half == 0) {
        float dd = dinv[node];
        unsigned us = G[node * 32 + m];          // self: g*dd = h*dinv^2
        ax += __uint_as_float(us << 16);
        ay += __uint_as_float(us & 0xffff0000u);
        float2 bb = ((const float2*)b)[m];
        float2 o;
        o.x = fmaxf(fmaf(ax, dd, bb.x), 0.f);
        o.y = fmaxf(fmaf(ay, dd, bb.y), 0.f);
        ((float2*)(outH + (size_t)node * 64))[m] = o;
    }
}

// ---- gather-2 + FC fused, per-wave; FC epilogue via b64/b128 LDS ops ----
__global__ __launch_bounds__(256) void gather_fc(
        const int* __restrict__ next, const int* __restrict__ esrc,
        const float* __restrict__ dinv, const unsigned* __restrict__ G,
        const float* __restrict__ b2, const float* __restrict__ Wfc,
        const float* __restrict__ bfc, float* __restrict__ out) {
    __shared__ float Wf2[16][68];     // [c][k], stride 68 (float4-aligned pad)
    __shared__ float h2s[4][72];      // stride 72: float4-aligned per wave
    int tid = threadIdx.x;
    #pragma unroll
    for (int i = tid; i < 1024; i += 256) {
        int c = i >> 6, k = i & 63;
        Wf2[c][k] = Wfc[k * 16 + c];  // 4 KB, L1-cached after first wave
    }
    __syncthreads();                  // Wf2 staging only
    int w = tid >> 6, lane = tid & 63, half = lane >> 5, m = lane & 31;
    int node = blockIdx.x * 4 + w;    // NN % 4 == 0
    int j0 = node ? next[node - 1] : 0;
    int e1 = next[node];
    float ax = 0.f, ay = 0.f;
    int j = j0 + half;
    for (; j + 6 < e1; j += 8) {
        int s0 = esrc[j], s1 = esrc[j + 2], s2 = esrc[j + 4], s3 = esrc[j + 6];
        unsigned u0 = G[s0 * 32 + m];
        unsigned u1 = G[s1 * 32 + m];
        unsigned u2 = G[s2 * 32 + m];
        unsigned u3 = G[s3 * 32 + m];
        ax += __uint_as_float(u0 << 16) + __uint_as_float(u1 << 16)
            + __uint_as_float(u2 << 16) + __uint_as_float(u3 << 16);
        ay += __uint_as_float(u0 & 0xffff0000u) + __uint_as_float(u1 & 0xffff0000u)
            + __uint_as_float(u2 & 0xffff0000u) + __uint_as_float(u3 & 0xffff0000u);
    }
    for (; j < e1; j += 2) {
        unsigned u = G[esrc[j] * 32 + m];
        ax += __uint_as_float(u << 16);
        ay += __uint_as_float(u & 0xffff0000u);
    }
    ax += __shfl_xor(ax, 32);
    ay += __shfl_xor(ay, 32);
    {
        float dd = dinv[node];
        unsigned us = G[node * 32 + m];
        ax += __uint_as_float(us << 16);
        ay += __uint_as_float(us & 0xffff0000u);
        float2 bb = ((const float2*)b2)[m];
        float hx = fmaxf(fmaf(ax, dd, bb.x), 0.f);
        float hy = fmaxf(fmaf(ay, dd, bb.y), 0.f);
        if (half == 0)
            *(float2*)&h2s[w][2 * m] = make_float2(hx, hy);   // one ds_write_b64
    }
    // wave-synchronous LDS (same wave wrote h2s[w]); split-k over 4 lane-groups
    int q = lane >> 4, c = lane & 15;
    float acc = 0.f;
    #pragma unroll
    for (int kk = 0; kk < 4; ++kk) {
        float4 hv = *(const float4*)&h2s[w][q * 16 + kk * 4];   // ds_read_b128
        float4 wv = *(const float4*)&Wf2[c][q * 16 + kk * 4];   // ds_read_b128
        acc += hv.x * wv.x + hv.y * wv.y + hv.z * wv.z + hv.w * wv.w;
    }
    acc += __shfl_xor(acc, 16);
    acc += __shfl_xor(acc, 32);
    if (lane < 16) out[node * 16 + c] = acc + bfc[c];
}

extern "C" void kernel_launch(void* const* d_in, const int* in_sizes, int n_in,
                              void* d_out, int out_size, void* d_ws, size_t ws_size,
                              hipStream_t stream) {
    const float* x   = (const float*)d_in[0];
    const int*   ei  = (const int*)d_in[1];
    const float* W1  = (const float*)d_in[2];
    const float* b1  = (const float*)d_in[3];
    const float* W2  = (const float*)d_in[4];
    const float* b2  = (const float*)d_in[5];
    const float* Wfc = (const float*)d_in[6];
    const float* bfc = (const float*)d_in[7];
    float* out = (float*)d_out;

    const int* src = ei;
    const int* dst = ei + NE;

    // ws: dinv[NN] | bbase[513] | next[NN] | C[196*512] | esrc[NE]
    //     | G[NN*32 u, 12.8MB] | bufB[NN*64 f32, 25.6MB]   (~46 MB)
    // pairs aliases bufB (consumed by bkt_csr before gather-1 writes bufB)
    float*    dinv  = (float*)d_ws;
    int*      bbase = (int*)(dinv + NN);
    int*      next  = bbase + NBP + 1;
    int*      C     = next + NN;
    int*      esrc  = C + NCHUNK * NBP;
    unsigned* G     = (unsigned*)(esrc + NE);
    float*    bufB  = (float*)(G + (size_t)NN * 32);
    int*      pairs = (int*)bufB;

    // ---- CSR build: 3 dispatches, no global atomics, deterministic ----
    hist_rows<<<NCHUNK, 256, 0, stream>>>(dst, C);
    place_scan<<<NCHUNK, 256, 0, stream>>>(src, dst, C, bbase, pairs);
    bkt_csr<<<NB, 256, 0, stream>>>(pairs, bbase, next, dinv, esrc);

    // ---- layer 1 ----
    gemm64g<<<NN / 16, 256, 0, stream>>>(x, W1, dinv, (ushort4*)G, NN);
    gather_bf16<<<(NN * 64) / 256, 256, 0, stream>>>(next, esrc, dinv, G, b1, bufB, NN);

    // ---- layer 2 + FC head (fused, per-wave) ----
    gemm64g<<<NN / 16, 256, 0, stream>>>(bufB, W2, dinv, (ushort4*)G, NN);
    gather_fc<<<NN / 4, 256, 0, stream>>>(next, esrc, dinv, G, b2, Wfc, bfc, out);
}

// Round 12
// 300.166 us; speedup vs baseline: 1.1043x; 1.1043x over previous
//
#include <hip/hip_runtime.h>

#define NN 100000
#define NE 1600000
#define NB 391              // ceil(NN/256) node-buckets of 256 dst nodes
#define NBP 512             // padded bucket count (pow2 for scans)
#define CHUNK 4096
#define NCHUNK 391          // ceil(NE/CHUNK)

static __device__ __forceinline__ unsigned short f2bf(float f) {
    unsigned u = __float_as_uint(f);
    u += 0x7fffu + ((u >> 16) & 1u);   // RNE
    return (unsigned short)(u >> 16);
}

// ---------------- A0: zero bucket counters ----------------
__global__ void zero_bkt(int* __restrict__ cnt) {
    int t = blockIdx.x * blockDim.x + threadIdx.x;
    if (t < NBP) cnt[t] = 0;
}

// ---------------- A1: bucket histogram (LDS-combined) ----------------
__global__ __launch_bounds__(256) void bkt_hist(const int* __restrict__ dst,
                                                int* __restrict__ cnt) {
    __shared__ int h[NBP];
    int t = threadIdx.x;
    h[t] = 0; h[t + 256] = 0;
    __syncthreads();
    int base = blockIdx.x * CHUNK;
    int end = min(base + CHUNK, NE);
    for (int e = base + t; e < end; e += 256) atomicAdd(&h[dst[e] >> 8], 1);
    __syncthreads();
    if (h[t]) atomicAdd(&cnt[t], h[t]);
    if (h[t + 256]) atomicAdd(&cnt[t + 256], h[t + 256]);
}

// ---------------- A2: scan bucket counts -> base, next ----------------
__global__ __launch_bounds__(512) void bkt_scan(const int* __restrict__ cnt,
                                                int* __restrict__ base,
                                                int* __restrict__ nxt) {
    __shared__ int buf[2][512];
    int t = threadIdx.x;
    int v = cnt[t];
    int pi = 0;
    buf[0][t] = v;
    __syncthreads();
    for (int off = 1; off < 512; off <<= 1) {
        int add = (t >= off) ? buf[pi][t - off] : 0;
        buf[1 - pi][t] = buf[pi][t] + add;
        pi ^= 1;
        __syncthreads();
    }
    int ex = buf[pi][t] - v;
    base[t] = ex;
    nxt[t] = ex;
    if (t == 511) base[512] = buf[pi][511];   // == NE
}

// ---------------- A3: placement — direct scatter into claimed regions ----------------
__global__ __launch_bounds__(256) void bkt_place(const int* __restrict__ src,
                                                 const int* __restrict__ dst,
                                                 int* __restrict__ bnext,
                                                 int* __restrict__ pairs) {
    __shared__ int lcnt[NBP];
    __shared__ int lnext[NBP];
    int t = threadIdx.x;
    lcnt[t] = 0; lcnt[t + 256] = 0;
    __syncthreads();
    int base = blockIdx.x * CHUNK;
    int end = min(base + CHUNK, NE);
    for (int e = base + t; e < end; e += 256) atomicAdd(&lcnt[dst[e] >> 8], 1);
    __syncthreads();
    {
        int v0 = lcnt[t], v1 = lcnt[t + 256];
        lnext[t]       = v0 ? atomicAdd(&bnext[t], v0) : 0;
        lnext[t + 256] = v1 ? atomicAdd(&bnext[t + 256], v1) : 0;
    }
    __syncthreads();
    for (int e = base + t; e < end; e += 256) {
        int d = dst[e];
        int p = atomicAdd(&lnext[d >> 8], 1);
        pairs[p] = src[e] | ((d & 255) << 17);
    }
}

// ---------------- B: per-bucket CSR build + dinv ----------------
__global__ __launch_bounds__(256) void bkt_csr(const int* __restrict__ pairs,
                                               const int* __restrict__ base,
                                               int* __restrict__ next,
                                               float* __restrict__ dinv,
                                               int* __restrict__ esrc) {
    __shared__ int cnt[256];
    __shared__ int sbuf[2][256];
    __shared__ int nxt[256];
    int b = blockIdx.x;
    int e0 = base[b], e1 = base[b + 1];
    int t = threadIdx.x;
    cnt[t] = 0;
    __syncthreads();
    for (int i = e0 + t; i < e1; i += 256) atomicAdd(&cnt[pairs[i] >> 17], 1);
    __syncthreads();
    int v = cnt[t];
    int pi = 0; sbuf[0][t] = v; __syncthreads();
    for (int off = 1; off < 256; off <<= 1) {
        int add = (t >= off) ? sbuf[pi][t - off] : 0;
        sbuf[1 - pi][t] = sbuf[pi][t] + add;
        pi ^= 1;
        __syncthreads();
    }
    int incl = sbuf[pi][t];
    int node = b * 256 + t;
    if (node < NN) {
        next[node] = e0 + incl;
        dinv[node] = rsqrtf((float)v + 1.0f);
    }
    nxt[t] = e0 + incl - v;
    __syncthreads();
    for (int i = e0 + t; i < e1; i += 256) {
        int w = pairs[i];
        int p = atomicAdd(&nxt[w >> 17], 1);
        esrc[p] = w & 0x1FFFF;
    }
}

// ---------------- GEMM [n,64]@[64,64] -> bf16 g = acc*dinv ----------------
__global__ __launch_bounds__(256) void gemm64g(const float* __restrict__ X,
                                               const float* __restrict__ W,
                                               const float* __restrict__ dinv,
                                               ushort4* __restrict__ G, int n) {
    __shared__ float4 Ws[64][16];
    __shared__ float  Xs[16][68];
    int tid = threadIdx.x;
    const float4* W4 = (const float4*)W;
    #pragma unroll
    for (int i = tid; i < 64 * 16; i += 256) Ws[i >> 4][i & 15] = W4[i];
    {
        int rr = tid >> 4, q = tid & 15;
        int node = blockIdx.x * 16 + rr;
        float4 v = ((const float4*)(X + (size_t)node * 64))[q];
        *(float4*)&Xs[rr][q * 4] = v;
    }
    __syncthreads();
    int r = tid >> 4, cq = tid & 15;
    float4 acc = {0.f, 0.f, 0.f, 0.f};
    #pragma unroll
    for (int k = 0; k < 64; ++k) {
        float x  = Xs[r][k];
        float4 w = Ws[k][cq];
        acc.x += x * w.x; acc.y += x * w.y; acc.z += x * w.z; acc.w += x * w.w;
    }
    int node = blockIdx.x * 16 + r;
    float dd = dinv[node];
    ushort4 pk;
    pk.x = f2bf(acc.x * dd); pk.y = f2bf(acc.y * dd);
    pk.z = f2bf(acc.z * dd); pk.w = f2bf(acc.w * dd);
    G[(size_t)node * 16 + cq] = pk;
}

// ---------------- gather (bf16): agg + self + bias + relu -> fp32 ----------------
// one independent wave per dst node — no cross-wave barriers
__global__ __launch_bounds__(256) void gather_bf16(
        const int* __restrict__ next, const int* __restrict__ esrc,
        const float* __restrict__ dinv, const unsigned* __restrict__ G,
        const float* __restrict__ b, float* __restrict__ outH, int n) {
    int node = (int)((blockIdx.x * blockDim.x + threadIdx.x) >> 6);
    if (node >= n) return;
    int lane = threadIdx.x & 63;
    int half = lane >> 5, m = lane & 31;
    int j0 = node ? next[node - 1] : 0;
    int e1 = next[node];
    float ax = 0.f, ay = 0.f;
    int j = j0 + half;
    for (; j + 6 < e1; j += 8) {
        int s0 = esrc[j], s1 = esrc[j + 2], s2 = esrc[j + 4], s3 = esrc[j + 6];
        unsigned u0 = G[s0 * 32 + m];
        unsigned u1 = G[s1 * 32 + m];
        unsigned u2 = G[s2 * 32 + m];
        unsigned u3 = G[s3 * 32 + m];
        ax += __uint_as_float(u0 << 16) + __uint_as_float(u1 << 16)
            + __uint_as_float(u2 << 16) + __uint_as_float(u3 << 16);
        ay += __uint_as_float(u0 & 0xffff0000u) + __uint_as_float(u1 & 0xffff0000u)
            + __uint_as_float(u2 & 0xffff0000u) + __uint_as_float(u3 & 0xffff0000u);
    }
    for (; j < e1; j += 2) {
        unsigned u = G[esrc[j] * 32 + m];
        ax += __uint_as_float(u << 16);
        ay += __uint_as_float(u & 0xffff0000u);
    }
    ax += __shfl_xor(ax, 32);
    ay += __shfl_xor(ay, 32);
    if (half == 0) {
        float dd = dinv[node];
        unsigned us = G[node * 32 + m];          // self: g*dd = h*dinv^2
        ax += __uint_as_float(us << 16);
        ay += __uint_as_float(us & 0xffff0000u);
        float2 bb = ((const float2*)b)[m];
        float2 o;
        o.x = fmaxf(fmaf(ax, dd, bb.x), 0.f);
        o.y = fmaxf(fmaf(ay, dd, bb.y), 0.f);
        ((float2*)(outH + (size_t)node * 64))[m] = o;
    }
}

// ---------------- gather-2 + FC fused: ZERO LDS, ZERO barriers ----------------
// After the xor-32 merge every lane holds h[2m],h[2m+1]. Lane (q,c) keeps its
// 16 W values in registers (coalesced global preload, L1-hot) and pulls h via
// 16 shuffles; 2 xor-shuffles reduce the 4 k-groups; lanes 0-15 store.
__global__ __launch_bounds__(256) void gather_fc(
        const int* __restrict__ next, const int* __restrict__ esrc,
        const float* __restrict__ dinv, const unsigned* __restrict__ G,
        const float* __restrict__ b2, const float* __restrict__ Wfc,
        const float* __restrict__ bfc, float* __restrict__ out) {
    int tid = threadIdx.x;
    int w = tid >> 6, lane = tid & 63, half = lane >> 5, m = lane & 31;
    int q = lane >> 4, c = lane & 15;
    int node = blockIdx.x * 4 + w;    // NN % 4 == 0
    // preload W[k][c] for k in [16q, 16q+16): per-instruction the wave reads
    // 4 x 64 B contiguous segments — coalesced; entire Wfc is 4 KB, L1-hot.
    float Wreg[16];
    #pragma unroll
    for (int i = 0; i < 16; ++i) Wreg[i] = Wfc[(q * 16 + i) * 16 + c];
    int j0 = node ? next[node - 1] : 0;
    int e1 = next[node];
    float ax = 0.f, ay = 0.f;
    int j = j0 + half;
    for (; j + 6 < e1; j += 8) {
        int s0 = esrc[j], s1 = esrc[j + 2], s2 = esrc[j + 4], s3 = esrc[j + 6];
        unsigned u0 = G[s0 * 32 + m];
        unsigned u1 = G[s1 * 32 + m];
        unsigned u2 = G[s2 * 32 + m];
        unsigned u3 = G[s3 * 32 + m];
        ax += __uint_as_float(u0 << 16) + __uint_as_float(u1 << 16)
            + __uint_as_float(u2 << 16) + __uint_as_float(u3 << 16);
        ay += __uint_as_float(u0 & 0xffff0000u) + __uint_as_float(u1 & 0xffff0000u)
            + __uint_as_float(u2 & 0xffff0000u) + __uint_as_float(u3 & 0xffff0000u);
    }
    for (; j < e1; j += 2) {
        unsigned u = G[esrc[j] * 32 + m];
        ax += __uint_as_float(u << 16);
        ay += __uint_as_float(u & 0xffff0000u);
    }
    ax += __shfl_xor(ax, 32);
    ay += __shfl_xor(ay, 32);
    // ALL lanes compute h (both halves hold identical values per m)
    float dd = dinv[node];
    unsigned us = G[node * 32 + m];              // self: g*dd = h*dinv^2
    ax += __uint_as_float(us << 16);
    ay += __uint_as_float(us & 0xffff0000u);
    float2 bb = ((const float2*)b2)[m];
    float hx = fmaxf(fmaf(ax, dd, bb.x), 0.f);   // h[2m]
    float hy = fmaxf(fmaf(ay, dd, bb.y), 0.f);   // h[2m+1]
    // FC partial over k in [16q, 16q+16): h pairs live in lanes q*8+j
    float acc = 0.f;
    #pragma unroll
    for (int jj = 0; jj < 8; ++jj) {
        int sl = q * 8 + jj;
        acc = fmaf(__shfl(hx, sl), Wreg[2 * jj],     acc);
        acc = fmaf(__shfl(hy, sl), Wreg[2 * jj + 1], acc);
    }
    acc += __shfl_xor(acc, 16);   // combine q pairs
    acc += __shfl_xor(acc, 32);
    if (lane < 16) out[node * 16 + c] = acc + bfc[c];
}

extern "C" void kernel_launch(void* const* d_in, const int* in_sizes, int n_in,
                              void* d_out, int out_size, void* d_ws, size_t ws_size,
                              hipStream_t stream) {
    const float* x   = (const float*)d_in[0];
    const int*   ei  = (const int*)d_in[1];
    const float* W1  = (const float*)d_in[2];
    const float* b1  = (const float*)d_in[3];
    const float* W2  = (const float*)d_in[4];
    const float* b2  = (const float*)d_in[5];
    const float* Wfc = (const float*)d_in[6];
    const float* bfc = (const float*)d_in[7];
    float* out = (float*)d_out;

    const int* src = ei;
    const int* dst = ei + NE;

    // ws: dinv[NN] | bcnt[512] | bbase[513] | bnext[512] | next[NN] | esrc[NE]
    //     | G[NN*32 u, 12.8MB] | bufB[NN*64 f32, 25.6MB]   (~46 MB)
    // pairs aliases bufB (consumed by bkt_csr before gather-1 writes bufB)
    float*    dinv  = (float*)d_ws;
    int*      bcnt  = (int*)(dinv + NN);
    int*      bbase = bcnt + NBP;
    int*      bnext = bbase + NBP + 1;
    int*      next  = bnext + NBP;
    int*      esrc  = next + NN;
    unsigned* G     = (unsigned*)(esrc + NE);
    float*    bufB  = (float*)(G + (size_t)NN * 32);
    int*      pairs = (int*)bufB;

    // ---- CSR build (R10-proven) ----
    zero_bkt<<<2, 256, 0, stream>>>(bcnt);
    bkt_hist<<<NCHUNK, 256, 0, stream>>>(dst, bcnt);
    bkt_scan<<<1, 512, 0, stream>>>(bcnt, bbase, bnext);
    bkt_place<<<NCHUNK, 256, 0, stream>>>(src, dst, bnext, pairs);
    bkt_csr<<<NB, 256, 0, stream>>>(pairs, bbase, next, dinv, esrc);

    // ---- layer 1 ----
    gemm64g<<<NN / 16, 256, 0, stream>>>(x, W1, dinv, (ushort4*)G, NN);
    gather_bf16<<<(NN * 64) / 256, 256, 0, stream>>>(next, esrc, dinv, G, b1, bufB, NN);

    // ---- layer 2 + FC head (fused, register/shuffle epilogue) ----
    gemm64g<<<NN / 16, 256, 0, stream>>>(bufB, W2, dinv, (ushort4*)G, NN);
    gather_fc<<<NN / 4, 256, 0, stream>>>(next, esrc, dinv, G, b2, Wfc, bfc, out);
}

// Round 13
// 296.740 us; speedup vs baseline: 1.1170x; 1.0115x over previous
//
#include <hip/hip_runtime.h>

#define NN 100000
#define NE 1600000
#define NB 391              // ceil(NN/256) node-buckets of 256 dst nodes
#define NBP 512             // padded bucket count (pow2 for scans)
#define CHUNK 4096
#define NCHUNK 391          // ceil(NE/CHUNK)

static __device__ __forceinline__ unsigned short f2bf(float f) {
    unsigned u = __float_as_uint(f);
    u += 0x7fffu + ((u >> 16) & 1u);   // RNE
    return (unsigned short)(u >> 16);
}
static __device__ __forceinline__ float bflo(unsigned u) { return __uint_as_float(u << 16); }
static __device__ __forceinline__ float bfhi(unsigned u) { return __uint_as_float(u & 0xffff0000u); }

// ---------------- A0: zero bucket counters ----------------
__global__ void zero_bkt(int* __restrict__ cnt) {
    int t = blockIdx.x * blockDim.x + threadIdx.x;
    if (t < NBP) cnt[t] = 0;
}

// ---------------- A1: bucket histogram (LDS-combined) ----------------
__global__ __launch_bounds__(256) void bkt_hist(const int* __restrict__ dst,
                                                int* __restrict__ cnt) {
    __shared__ int h[NBP];
    int t = threadIdx.x;
    h[t] = 0; h[t + 256] = 0;
    __syncthreads();
    int base = blockIdx.x * CHUNK;
    int end = min(base + CHUNK, NE);
    for (int e = base + t; e < end; e += 256) atomicAdd(&h[dst[e] >> 8], 1);
    __syncthreads();
    if (h[t]) atomicAdd(&cnt[t], h[t]);
    if (h[t + 256]) atomicAdd(&cnt[t + 256], h[t + 256]);
}

// ---------------- A2: scan bucket counts -> base, next ----------------
__global__ __launch_bounds__(512) void bkt_scan(const int* __restrict__ cnt,
                                                int* __restrict__ base,
                                                int* __restrict__ nxt) {
    __shared__ int buf[2][512];
    int t = threadIdx.x;
    int v = cnt[t];
    int pi = 0;
    buf[0][t] = v;
    __syncthreads();
    for (int off = 1; off < 512; off <<= 1) {
        int add = (t >= off) ? buf[pi][t - off] : 0;
        buf[1 - pi][t] = buf[pi][t] + add;
        pi ^= 1;
        __syncthreads();
    }
    int ex = buf[pi][t] - v;
    base[t] = ex;
    nxt[t] = ex;
    if (t == 511) base[512] = buf[pi][511];   // == NE
}

// ---------------- A3: placement — direct scatter into claimed regions ----------------
__global__ __launch_bounds__(256) void bkt_place(const int* __restrict__ src,
                                                 const int* __restrict__ dst,
                                                 int* __restrict__ bnext,
                                                 int* __restrict__ pairs) {
    __shared__ int lcnt[NBP];
    __shared__ int lnext[NBP];
    int t = threadIdx.x;
    lcnt[t] = 0; lcnt[t + 256] = 0;
    __syncthreads();
    int base = blockIdx.x * CHUNK;
    int end = min(base + CHUNK, NE);
    for (int e = base + t; e < end; e += 256) atomicAdd(&lcnt[dst[e] >> 8], 1);
    __syncthreads();
    {
        int v0 = lcnt[t], v1 = lcnt[t + 256];
        lnext[t]       = v0 ? atomicAdd(&bnext[t], v0) : 0;
        lnext[t + 256] = v1 ? atomicAdd(&bnext[t + 256], v1) : 0;
    }
    __syncthreads();
    for (int e = base + t; e < end; e += 256) {
        int d = dst[e];
        int p = atomicAdd(&lnext[d >> 8], 1);
        pairs[p] = src[e] | ((d & 255) << 17);
    }
}

// ---------------- B: per-bucket CSR build + dinv ----------------
__global__ __launch_bounds__(256) void bkt_csr(const int* __restrict__ pairs,
                                               const int* __restrict__ base,
                                               int* __restrict__ next,
                                               float* __restrict__ dinv,
                                               int* __restrict__ esrc) {
    __shared__ int cnt[256];
    __shared__ int sbuf[2][256];
    __shared__ int nxt[256];
    int b = blockIdx.x;
    int e0 = base[b], e1 = base[b + 1];
    int t = threadIdx.x;
    cnt[t] = 0;
    __syncthreads();
    for (int i = e0 + t; i < e1; i += 256) atomicAdd(&cnt[pairs[i] >> 17], 1);
    __syncthreads();
    int v = cnt[t];
    int pi = 0; sbuf[0][t] = v; __syncthreads();
    for (int off = 1; off < 256; off <<= 1) {
        int add = (t >= off) ? sbuf[pi][t - off] : 0;
        sbuf[1 - pi][t] = sbuf[pi][t] + add;
        pi ^= 1;
        __syncthreads();
    }
    int incl = sbuf[pi][t];
    int node = b * 256 + t;
    if (node < NN) {
        next[node] = e0 + incl;
        dinv[node] = rsqrtf((float)v + 1.0f);
    }
    nxt[t] = e0 + incl - v;
    __syncthreads();
    for (int i = e0 + t; i < e1; i += 256) {
        int w = pairs[i];
        int p = atomicAdd(&nxt[w >> 17], 1);
        esrc[p] = w & 0x1FFFF;
    }
}

// ---------------- GEMM (fp32 in) [n,64]@[64,64] -> bf16 g = acc*dinv ----------------
__global__ __launch_bounds__(256) void gemm64g(const float* __restrict__ X,
                                               const float* __restrict__ W,
                                               const float* __restrict__ dinv,
                                               ushort4* __restrict__ G, int n) {
    __shared__ float4 Ws[64][16];
    __shared__ float  Xs[16][68];
    int tid = threadIdx.x;
    const float4* W4 = (const float4*)W;
    #pragma unroll
    for (int i = tid; i < 64 * 16; i += 256) Ws[i >> 4][i & 15] = W4[i];
    {
        int rr = tid >> 4, q = tid & 15;
        int node = blockIdx.x * 16 + rr;
        float4 v = ((const float4*)(X + (size_t)node * 64))[q];
        *(float4*)&Xs[rr][q * 4] = v;
    }
    __syncthreads();
    int r = tid >> 4, cq = tid & 15;
    float4 acc = {0.f, 0.f, 0.f, 0.f};
    #pragma unroll
    for (int k = 0; k < 64; ++k) {
        float x  = Xs[r][k];
        float4 w = Ws[k][cq];
        acc.x += x * w.x; acc.y += x * w.y; acc.z += x * w.z; acc.w += x * w.w;
    }
    int node = blockIdx.x * 16 + r;
    float dd = dinv[node];
    ushort4 pk;
    pk.x = f2bf(acc.x * dd); pk.y = f2bf(acc.y * dd);
    pk.z = f2bf(acc.z * dd); pk.w = f2bf(acc.w * dd);
    G[(size_t)node * 16 + cq] = pk;
}

// ---------------- GEMM (bf16 in) [n,64]@[64,64] -> bf16 g = acc*dinv ----------------
__global__ __launch_bounds__(256) void gemm64gb(const ushort4* __restrict__ X16,
                                                const float* __restrict__ W,
                                                const float* __restrict__ dinv,
                                                ushort4* __restrict__ G, int n) {
    __shared__ float4 Ws[64][16];
    __shared__ float  Xs[16][68];
    int tid = threadIdx.x;
    const float4* W4 = (const float4*)W;
    #pragma unroll
    for (int i = tid; i < 64 * 16; i += 256) Ws[i >> 4][i & 15] = W4[i];
    {
        int rr = tid >> 4, q = tid & 15;
        int node = blockIdx.x * 16 + rr;
        ushort4 u = X16[(size_t)node * 16 + q];
        float4 v;
        v.x = __uint_as_float((unsigned)u.x << 16);
        v.y = __uint_as_float((unsigned)u.y << 16);
        v.z = __uint_as_float((unsigned)u.z << 16);
        v.w = __uint_as_float((unsigned)u.w << 16);
        *(float4*)&Xs[rr][q * 4] = v;
    }
    __syncthreads();
    int r = tid >> 4, cq = tid & 15;
    float4 acc = {0.f, 0.f, 0.f, 0.f};
    #pragma unroll
    for (int k = 0; k < 64; ++k) {
        float x  = Xs[r][k];
        float4 w = Ws[k][cq];
        acc.x += x * w.x; acc.y += x * w.y; acc.z += x * w.z; acc.w += x * w.w;
    }
    int node = blockIdx.x * 16 + r;
    float dd = dinv[node];
    ushort4 pk;
    pk.x = f2bf(acc.x * dd); pk.y = f2bf(acc.y * dd);
    pk.z = f2bf(acc.z * dd); pk.w = f2bf(acc.w * dd);
    G[(size_t)node * 16 + cq] = pk;
}

// ---------------- gather-1 (uint2 lanes): agg + self + bias + relu -> bf16 h1 ----------------
// wave per node; lane = (e in 0..3, m in 0..15); lane loads G2[s_e*16+m] (8 B,
// feats 4m..4m+3). 4 edges per load instr; xor16+xor32 combine edge-groups.
__global__ __launch_bounds__(256) void gather_bf16(
        const int* __restrict__ next, const int* __restrict__ esrc,
        const float* __restrict__ dinv, const uint2* __restrict__ G2,
        const float* __restrict__ b, ushort4* __restrict__ outH, int n) {
    int node = (int)((blockIdx.x * blockDim.x + threadIdx.x) >> 6);
    if (node >= n) return;
    int lane = threadIdx.x & 63;
    int e = lane >> 4, m = lane & 15;
    int j0 = node ? next[node - 1] : 0;
    int e1 = next[node];
    float4 av = {0.f, 0.f, 0.f, 0.f};
    int j = j0 + e;
    for (; j + 4 < e1; j += 8) {
        int s0 = esrc[j], s1 = esrc[j + 4];
        uint2 u0 = G2[s0 * 16 + m];
        uint2 u1 = G2[s1 * 16 + m];
        av.x += bflo(u0.x) + bflo(u1.x);
        av.y += bfhi(u0.x) + bfhi(u1.x);
        av.z += bflo(u0.y) + bflo(u1.y);
        av.w += bfhi(u0.y) + bfhi(u1.y);
    }
    for (; j < e1; j += 4) {
        uint2 u = G2[esrc[j] * 16 + m];
        av.x += bflo(u.x); av.y += bfhi(u.x);
        av.z += bflo(u.y); av.w += bfhi(u.y);
    }
    av.x += __shfl_xor(av.x, 16); av.y += __shfl_xor(av.y, 16);
    av.z += __shfl_xor(av.z, 16); av.w += __shfl_xor(av.w, 16);
    av.x += __shfl_xor(av.x, 32); av.y += __shfl_xor(av.y, 32);
    av.z += __shfl_xor(av.z, 32); av.w += __shfl_xor(av.w, 32);
    if (e == 0) {
        float dd = dinv[node];
        uint2 us = G2[node * 16 + m];            // self: g*dd = h*dinv^2
        av.x += bflo(us.x); av.y += bfhi(us.x);
        av.z += bflo(us.y); av.w += bfhi(us.y);
        float4 bb = ((const float4*)b)[m];
        ushort4 pk;
        pk.x = f2bf(fmaxf(fmaf(av.x, dd, bb.x), 0.f));
        pk.y = f2bf(fmaxf(fmaf(av.y, dd, bb.y), 0.f));
        pk.z = f2bf(fmaxf(fmaf(av.z, dd, bb.z), 0.f));
        pk.w = f2bf(fmaxf(fmaf(av.w, dd, bb.w), 0.f));
        outH[(size_t)node * 16 + m] = pk;        // 16 lanes x 8 B = 128 B/node
    }
}

// ---------------- gather-2 + FC fused (uint2 lanes, zero LDS/barriers) ----------------
__global__ __launch_bounds__(256) void gather_fc(
        const int* __restrict__ next, const int* __restrict__ esrc,
        const float* __restrict__ dinv, const uint2* __restrict__ G2,
        const float* __restrict__ b2, const float* __restrict__ Wfc,
        const float* __restrict__ bfc, float* __restrict__ out) {
    int tid = threadIdx.x;
    int w = tid >> 6, lane = tid & 63;
    int e = lane >> 4, m = lane & 15;
    int q = e, c = m;                 // FC roles: k-group q, output col c
    int node = blockIdx.x * 4 + w;    // NN % 4 == 0
    float Wreg[16];
    #pragma unroll
    for (int i = 0; i < 16; ++i) Wreg[i] = Wfc[(q * 16 + i) * 16 + c];
    int j0 = node ? next[node - 1] : 0;
    int e1 = next[node];
    float4 av = {0.f, 0.f, 0.f, 0.f};
    int j = j0 + e;
    for (; j + 4 < e1; j += 8) {
        int s0 = esrc[j], s1 = esrc[j + 4];
        uint2 u0 = G2[s0 * 16 + m];
        uint2 u1 = G2[s1 * 16 + m];
        av.x += bflo(u0.x) + bflo(u1.x);
        av.y += bfhi(u0.x) + bfhi(u1.x);
        av.z += bflo(u0.y) + bflo(u1.y);
        av.w += bfhi(u0.y) + bfhi(u1.y);
    }
    for (; j < e1; j += 4) {
        uint2 u = G2[esrc[j] * 16 + m];
        av.x += bflo(u.x); av.y += bfhi(u.x);
        av.z += bflo(u.y); av.w += bfhi(u.y);
    }
    av.x += __shfl_xor(av.x, 16); av.y += __shfl_xor(av.y, 16);
    av.z += __shfl_xor(av.z, 16); av.w += __shfl_xor(av.w, 16);
    av.x += __shfl_xor(av.x, 32); av.y += __shfl_xor(av.y, 32);
    av.z += __shfl_xor(av.z, 32); av.w += __shfl_xor(av.w, 32);
    // ALL lanes: self + bias + relu -> h feats (4m..4m+3) in av
    float dd = dinv[node];
    uint2 us = G2[node * 16 + m];
    av.x += bflo(us.x); av.y += bfhi(us.x);
    av.z += bflo(us.y); av.w += bfhi(us.y);
    float4 bb = ((const float4*)b2)[m];
    av.x = fmaxf(fmaf(av.x, dd, bb.x), 0.f);
    av.y = fmaxf(fmaf(av.y, dd, bb.y), 0.f);
    av.z = fmaxf(fmaf(av.z, dd, bb.z), 0.f);
    av.w = fmaxf(fmaf(av.w, dd, bb.w), 0.f);
    // FC partial over k in [16q,16q+16): h[16q+4i+ii] = comp ii of lane 4q+i
    float acc = 0.f;
    #pragma unroll
    for (int i = 0; i < 4; ++i) {
        int sl = 4 * q + i;
        acc = fmaf(__shfl(av.x, sl), Wreg[4 * i],     acc);
        acc = fmaf(__shfl(av.y, sl), Wreg[4 * i + 1], acc);
        acc = fmaf(__shfl(av.z, sl), Wreg[4 * i + 2], acc);
        acc = fmaf(__shfl(av.w, sl), Wreg[4 * i + 3], acc);
    }
    acc += __shfl_xor(acc, 16);
    acc += __shfl_xor(acc, 32);
    if (lane < 16) out[node * 16 + c] = acc + bfc[c];
}

extern "C" void kernel_launch(void* const* d_in, const int* in_sizes, int n_in,
                              void* d_out, int out_size, void* d_ws, size_t ws_size,
                              hipStream_t stream) {
    const float* x   = (const float*)d_in[0];
    const int*   ei  = (const int*)d_in[1];
    const float* W1  = (const float*)d_in[2];
    const float* b1  = (const float*)d_in[3];
    const float* W2  = (const float*)d_in[4];
    const float* b2  = (const float*)d_in[5];
    const float* Wfc = (const float*)d_in[6];
    const float* bfc = (const float*)d_in[7];
    float* out = (float*)d_out;

    const int* src = ei;
    const int* dst = ei + NE;

    // ws: dinv[NN] | bcnt[512] | bbase[513] | bnext[512] | next[NN] | esrc[NE]
    //     | G[NN*32 u, 12.8MB] | bufB[NN*64 bf16, 12.8MB]   (~33 MB)
    // pairs aliases bufB (consumed by bkt_csr before gather-1 writes bufB)
    float*    dinv  = (float*)d_ws;
    int*      bcnt  = (int*)(dinv + NN);
    int*      bbase = bcnt + NBP;
    int*      bnext = bbase + NBP + 1;
    int*      next  = bnext + NBP;
    int*      esrc  = next + NN;
    unsigned* G     = (unsigned*)(esrc + NE);
    ushort4*  bufB  = (ushort4*)(G + (size_t)NN * 32);
    int*      pairs = (int*)bufB;

    // ---- CSR build (R10/R12-proven) ----
    zero_bkt<<<2, 256, 0, stream>>>(bcnt);
    bkt_hist<<<NCHUNK, 256, 0, stream>>>(dst, bcnt);
    bkt_scan<<<1, 512, 0, stream>>>(bcnt, bbase, bnext);
    bkt_place<<<NCHUNK, 256, 0, stream>>>(src, dst, bnext, pairs);
    bkt_csr<<<NB, 256, 0, stream>>>(pairs, bbase, next, dinv, esrc);

    // ---- layer 1: gemm(fp32 x) -> G ; gather -> bf16 h1 ----
    gemm64g<<<NN / 16, 256, 0, stream>>>(x, W1, dinv, (ushort4*)G, NN);
    gather_bf16<<<(NN * 64) / 256, 256, 0, stream>>>(next, esrc, dinv, (const uint2*)G, b1, bufB, NN);

    // ---- layer 2: gemm(bf16 h1) -> G ; gather + FC -> out ----
    gemm64gb<<<NN / 16, 256, 0, stream>>>(bufB, W2, dinv, (ushort4*)G, NN);
    gather_fc<<<NN / 4, 256, 0, stream>>>(next, esrc, dinv, (const uint2*)G, b2, Wfc, bfc, out);
}

// Round 14
// 282.290 us; speedup vs baseline: 1.1742x; 1.0512x over previous
//
#include <hip/hip_runtime.h>

#define NN 100000
#define NE 1600000
#define NB 391              // ceil(NN/256) node-buckets of 256 dst nodes
#define NBP 512             // padded bucket count (pow2 for scans)
#define CHUNK 4096
#define NCHUNK 391          // ceil(NE/CHUNK)

static __device__ __forceinline__ unsigned short f2bf(float f) {
    unsigned u = __float_as_uint(f);
    u += 0x7fffu + ((u >> 16) & 1u);   // RNE
    return (unsigned short)(u >> 16);
}
static __device__ __forceinline__ float bflo(unsigned u) { return __uint_as_float(u << 16); }
static __device__ __forceinline__ float bfhi(unsigned u) { return __uint_as_float(u & 0xffff0000u); }

// ---------------- A0: zero bucket counters + relative cursors ----------------
__global__ void zero_bkt(int* __restrict__ p) {
    int t = blockIdx.x * blockDim.x + threadIdx.x;
    if (t < 2 * NBP) p[t] = 0;
}

// ---------------- A1: bucket histogram (LDS-combined) ----------------
__global__ __launch_bounds__(256) void bkt_hist(const int* __restrict__ dst,
                                                int* __restrict__ cnt) {
    __shared__ int h[NBP];
    int t = threadIdx.x;
    h[t] = 0; h[t + 256] = 0;
    __syncthreads();
    int base = blockIdx.x * CHUNK;
    int end = min(base + CHUNK, NE);
    for (int e = base + t; e < end; e += 256) atomicAdd(&h[dst[e] >> 8], 1);
    __syncthreads();
    if (h[t]) atomicAdd(&cnt[t], h[t]);
    if (h[t + 256]) atomicAdd(&cnt[t + 256], h[t + 256]);
}

// ---------------- A2: placement w/ inline redundant bucket scan ----------------
// Each block: chunk histogram -> redundant 512-entry scan of bcnt (L2-hot) ->
// claim exclusive region via bbase + atomicAdd(brel) -> direct scatter.
// Block 0 also emits bbase[] for bkt_csr.
__global__ __launch_bounds__(256) void bkt_place(const int* __restrict__ src,
                                                 const int* __restrict__ dst,
                                                 const int* __restrict__ bcnt,
                                                 int* __restrict__ brel,
                                                 int* __restrict__ bbase,
                                                 int* __restrict__ pairs) {
    __shared__ int lcnt[NBP];
    __shared__ int sA[NBP];
    __shared__ int sbuf[2][256];
    __shared__ int lnext[NBP];
    int t = threadIdx.x;
    lcnt[t] = 0; lcnt[t + 256] = 0;
    __syncthreads();
    int base = blockIdx.x * CHUNK;
    int end = min(base + CHUNK, NE);
    for (int e = base + t; e < end; e += 256) atomicAdd(&lcnt[dst[e] >> 8], 1);
    // redundant global-bucket scan (2 elems/thread, ping-pong over 256)
    int a0 = bcnt[2 * t], a1 = bcnt[2 * t + 1];
    int ps = a0 + a1;
    int pi = 0;
    sbuf[0][t] = ps;
    __syncthreads();   // also covers hist atomics
    for (int off = 1; off < 256; off <<= 1) {
        int add = (t >= off) ? sbuf[pi][t - off] : 0;
        sbuf[1 - pi][t] = sbuf[pi][t] + add;
        pi ^= 1;
        __syncthreads();
    }
    int incl = sbuf[pi][t];
    int ex = incl - ps;
    sA[2 * t]     = ex;
    sA[2 * t + 1] = ex + a0;
    if (blockIdx.x == 0) {
        bbase[2 * t] = ex;
        bbase[2 * t + 1] = ex + a0;
        if (t == 255) bbase[NBP] = incl;   // == NE
    }
    __syncthreads();
    {
        int v0 = lcnt[t], v1 = lcnt[t + 256];
        lnext[t]       = sA[t]       + (v0 ? atomicAdd(&brel[t], v0) : 0);
        lnext[t + 256] = sA[t + 256] + (v1 ? atomicAdd(&brel[t + 256], v1) : 0);
    }
    __syncthreads();
    for (int e = base + t; e < end; e += 256) {
        int d = dst[e];
        int p = atomicAdd(&lnext[d >> 8], 1);
        pairs[p] = src[e] | ((d & 255) << 17);
    }
}

// ---------------- B: per-bucket CSR build + dinv ----------------
__global__ __launch_bounds__(256) void bkt_csr(const int* __restrict__ pairs,
                                               const int* __restrict__ base,
                                               int* __restrict__ next,
                                               float* __restrict__ dinv,
                                               int* __restrict__ esrc) {
    __shared__ int cnt[256];
    __shared__ int sbuf[2][256];
    __shared__ int nxt[256];
    int b = blockIdx.x;
    int e0 = base[b], e1 = base[b + 1];
    int t = threadIdx.x;
    cnt[t] = 0;
    __syncthreads();
    for (int i = e0 + t; i < e1; i += 256) atomicAdd(&cnt[pairs[i] >> 17], 1);
    __syncthreads();
    int v = cnt[t];
    int pi = 0; sbuf[0][t] = v; __syncthreads();
    for (int off = 1; off < 256; off <<= 1) {
        int add = (t >= off) ? sbuf[pi][t - off] : 0;
        sbuf[1 - pi][t] = sbuf[pi][t] + add;
        pi ^= 1;
        __syncthreads();
    }
    int incl = sbuf[pi][t];
    int node = b * 256 + t;
    if (node < NN) {
        next[node] = e0 + incl;
        dinv[node] = rsqrtf((float)v + 1.0f);
    }
    nxt[t] = e0 + incl - v;
    __syncthreads();
    for (int i = e0 + t; i < e1; i += 256) {
        int w = pairs[i];
        int p = atomicAdd(&nxt[w >> 17], 1);
        esrc[p] = w & 0x1FFFF;
    }
}

// ---------------- GEMM (fp32 in) [n,64]@[64,64] -> bf16 g = acc*dinv ----------------
__global__ __launch_bounds__(256) void gemm64g(const float* __restrict__ X,
                                               const float* __restrict__ W,
                                               const float* __restrict__ dinv,
                                               ushort4* __restrict__ G, int n) {
    __shared__ float4 Ws[64][16];
    __shared__ float  Xs[16][68];
    int tid = threadIdx.x;
    const float4* W4 = (const float4*)W;
    #pragma unroll
    for (int i = tid; i < 64 * 16; i += 256) Ws[i >> 4][i & 15] = W4[i];
    {
        int rr = tid >> 4, q = tid & 15;
        int node = blockIdx.x * 16 + rr;
        float4 v = ((const float4*)(X + (size_t)node * 64))[q];
        *(float4*)&Xs[rr][q * 4] = v;
    }
    __syncthreads();
    int r = tid >> 4, cq = tid & 15;
    float4 acc = {0.f, 0.f, 0.f, 0.f};
    #pragma unroll
    for (int k = 0; k < 64; ++k) {
        float x  = Xs[r][k];
        float4 w = Ws[k][cq];
        acc.x += x * w.x; acc.y += x * w.y; acc.z += x * w.z; acc.w += x * w.w;
    }
    int node = blockIdx.x * 16 + r;
    float dd = dinv[node];
    ushort4 pk;
    pk.x = f2bf(acc.x * dd); pk.y = f2bf(acc.y * dd);
    pk.z = f2bf(acc.z * dd); pk.w = f2bf(acc.w * dd);
    G[(size_t)node * 16 + cq] = pk;
}

// ---------------- GEMM (bf16 in) [n,64]@[64,64] -> bf16 g = acc*dinv ----------------
__global__ __launch_bounds__(256) void gemm64gb(const ushort4* __restrict__ X16,
                                                const float* __restrict__ W,
                                                const float* __restrict__ dinv,
                                                ushort4* __restrict__ G, int n) {
    __shared__ float4 Ws[64][16];
    __shared__ float  Xs[16][68];
    int tid = threadIdx.x;
    const float4* W4 = (const float4*)W;
    #pragma unroll
    for (int i = tid; i < 64 * 16; i += 256) Ws[i >> 4][i & 15] = W4[i];
    {
        int rr = tid >> 4, q = tid & 15;
        int node = blockIdx.x * 16 + rr;
        ushort4 u = X16[(size_t)node * 16 + q];
        float4 v;
        v.x = __uint_as_float((unsigned)u.x << 16);
        v.y = __uint_as_float((unsigned)u.y << 16);
        v.z = __uint_as_float((unsigned)u.z << 16);
        v.w = __uint_as_float((unsigned)u.w << 16);
        *(float4*)&Xs[rr][q * 4] = v;
    }
    __syncthreads();
    int r = tid >> 4, cq = tid & 15;
    float4 acc = {0.f, 0.f, 0.f, 0.f};
    #pragma unroll
    for (int k = 0; k < 64; ++k) {
        float x  = Xs[r][k];
        float4 w = Ws[k][cq];
        acc.x += x * w.x; acc.y += x * w.y; acc.z += x * w.z; acc.w += x * w.w;
    }
    int node = blockIdx.x * 16 + r;
    float dd = dinv[node];
    ushort4 pk;
    pk.x = f2bf(acc.x * dd); pk.y = f2bf(acc.y * dd);
    pk.z = f2bf(acc.z * dd); pk.w = f2bf(acc.w * dd);
    G[(size_t)node * 16 + cq] = pk;
}

// ---------------- gather-1 (uint4 lanes): agg + self + bias + relu -> bf16 h1 ----------------
// wave per node; lane = (e in 0..7, m in 0..7); lane loads G4[s_e*8+m] (16 B,
// feats 8m..8m+7). 8 edges per load instr; xor8+xor16+xor32 combine e-groups.
__global__ __launch_bounds__(256) void gather_bf16(
        const int* __restrict__ next, const int* __restrict__ esrc,
        const float* __restrict__ dinv, const uint4* __restrict__ G4,
        const float* __restrict__ b, uint4* __restrict__ outH, int n) {
    int node = (int)((blockIdx.x * blockDim.x + threadIdx.x) >> 6);
    if (node >= n) return;
    int lane = threadIdx.x & 63;
    int e = lane >> 3, m = lane & 7;
    int j0 = node ? next[node - 1] : 0;
    int e1 = next[node];
    float a0 = 0.f, a1 = 0.f, a2 = 0.f, a3 = 0.f, a4 = 0.f, a5 = 0.f, a6 = 0.f, a7 = 0.f;
    int j = j0 + e;
    for (; j + 8 < e1; j += 16) {
        int s0 = esrc[j], s1 = esrc[j + 8];
        uint4 u0 = G4[s0 * 8 + m];
        uint4 u1 = G4[s1 * 8 + m];
        a0 += bflo(u0.x) + bflo(u1.x); a1 += bfhi(u0.x) + bfhi(u1.x);
        a2 += bflo(u0.y) + bflo(u1.y); a3 += bfhi(u0.y) + bfhi(u1.y);
        a4 += bflo(u0.z) + bflo(u1.z); a5 += bfhi(u0.z) + bfhi(u1.z);
        a6 += bflo(u0.w) + bflo(u1.w); a7 += bfhi(u0.w) + bfhi(u1.w);
    }
    for (; j < e1; j += 8) {
        uint4 u = G4[esrc[j] * 8 + m];
        a0 += bflo(u.x); a1 += bfhi(u.x); a2 += bflo(u.y); a3 += bfhi(u.y);
        a4 += bflo(u.z); a5 += bfhi(u.z); a6 += bflo(u.w); a7 += bfhi(u.w);
    }
    a0 += __shfl_xor(a0, 8);  a1 += __shfl_xor(a1, 8);  a2 += __shfl_xor(a2, 8);  a3 += __shfl_xor(a3, 8);
    a4 += __shfl_xor(a4, 8);  a5 += __shfl_xor(a5, 8);  a6 += __shfl_xor(a6, 8);  a7 += __shfl_xor(a7, 8);
    a0 += __shfl_xor(a0, 16); a1 += __shfl_xor(a1, 16); a2 += __shfl_xor(a2, 16); a3 += __shfl_xor(a3, 16);
    a4 += __shfl_xor(a4, 16); a5 += __shfl_xor(a5, 16); a6 += __shfl_xor(a6, 16); a7 += __shfl_xor(a7, 16);
    a0 += __shfl_xor(a0, 32); a1 += __shfl_xor(a1, 32); a2 += __shfl_xor(a2, 32); a3 += __shfl_xor(a3, 32);
    a4 += __shfl_xor(a4, 32); a5 += __shfl_xor(a5, 32); a6 += __shfl_xor(a6, 32); a7 += __shfl_xor(a7, 32);
    if (e == 0) {
        float dd = dinv[node];
        uint4 us = G4[node * 8 + m];             // self: g*dd = h*dinv^2
        a0 += bflo(us.x); a1 += bfhi(us.x); a2 += bflo(us.y); a3 += bfhi(us.y);
        a4 += bflo(us.z); a5 += bfhi(us.z); a6 += bflo(us.w); a7 += bfhi(us.w);
        float4 b0 = ((const float4*)b)[2 * m];
        float4 b1v = ((const float4*)b)[2 * m + 1];
        float h0 = fmaxf(fmaf(a0, dd, b0.x), 0.f);
        float h1 = fmaxf(fmaf(a1, dd, b0.y), 0.f);
        float h2 = fmaxf(fmaf(a2, dd, b0.z), 0.f);
        float h3 = fmaxf(fmaf(a3, dd, b0.w), 0.f);
        float h4 = fmaxf(fmaf(a4, dd, b1v.x), 0.f);
        float h5 = fmaxf(fmaf(a5, dd, b1v.y), 0.f);
        float h6 = fmaxf(fmaf(a6, dd, b1v.z), 0.f);
        float h7 = fmaxf(fmaf(a7, dd, b1v.w), 0.f);
        uint4 pk;
        pk.x = (unsigned)f2bf(h0) | ((unsigned)f2bf(h1) << 16);
        pk.y = (unsigned)f2bf(h2) | ((unsigned)f2bf(h3) << 16);
        pk.z = (unsigned)f2bf(h4) | ((unsigned)f2bf(h5) << 16);
        pk.w = (unsigned)f2bf(h6) | ((unsigned)f2bf(h7) << 16);
        outH[(size_t)node * 8 + m] = pk;         // 8 lanes x 16 B = 128 B/node
    }
}

// ---------------- gather-2 + FC fused (uint4 lanes, zero LDS/barriers) ----------------
__global__ __launch_bounds__(256) void gather_fc(
        const int* __restrict__ next, const int* __restrict__ esrc,
        const float* __restrict__ dinv, const uint4* __restrict__ G4,
        const float* __restrict__ b2, const float* __restrict__ Wfc,
        const float* __restrict__ bfc, float* __restrict__ out) {
    int tid = threadIdx.x;
    int w = tid >> 6, lane = tid & 63;
    int e = lane >> 3, m = lane & 7;
    int q = lane >> 4, c = lane & 15;    // FC roles
    int node = blockIdx.x * 4 + w;       // NN % 4 == 0
    float Wreg[16];
    #pragma unroll
    for (int i = 0; i < 16; ++i) Wreg[i] = Wfc[(q * 16 + i) * 16 + c];
    int j0 = node ? next[node - 1] : 0;
    int e1 = next[node];
    float a0 = 0.f, a1 = 0.f, a2 = 0.f, a3 = 0.f, a4 = 0.f, a5 = 0.f, a6 = 0.f, a7 = 0.f;
    int j = j0 + e;
    for (; j + 8 < e1; j += 16) {
        int s0 = esrc[j], s1 = esrc[j + 8];
        uint4 u0 = G4[s0 * 8 + m];
        uint4 u1 = G4[s1 * 8 + m];
        a0 += bflo(u0.x) + bflo(u1.x); a1 += bfhi(u0.x) + bfhi(u1.x);
        a2 += bflo(u0.y) + bflo(u1.y); a3 += bfhi(u0.y) + bfhi(u1.y);
        a4 += bflo(u0.z) + bflo(u1.z); a5 += bfhi(u0.z) + bfhi(u1.z);
        a6 += bflo(u0.w) + bflo(u1.w); a7 += bfhi(u0.w) + bfhi(u1.w);
    }
    for (; j < e1; j += 8) {
        uint4 u = G4[esrc[j] * 8 + m];
        a0 += bflo(u.x); a1 += bfhi(u.x); a2 += bflo(u.y); a3 += bfhi(u.y);
        a4 += bflo(u.z); a5 += bfhi(u.z); a6 += bflo(u.w); a7 += bfhi(u.w);
    }
    a0 += __shfl_xor(a0, 8);  a1 += __shfl_xor(a1, 8);  a2 += __shfl_xor(a2, 8);  a3 += __shfl_xor(a3, 8);
    a4 += __shfl_xor(a4, 8);  a5 += __shfl_xor(a5, 8);  a6 += __shfl_xor(a6, 8);  a7 += __shfl_xor(a7, 8);
    a0 += __shfl_xor(a0, 16); a1 += __shfl_xor(a1, 16); a2 += __shfl_xor(a2, 16); a3 += __shfl_xor(a3, 16);
    a4 += __shfl_xor(a4, 16); a5 += __shfl_xor(a5, 16); a6 += __shfl_xor(a6, 16); a7 += __shfl_xor(a7, 16);
    a0 += __shfl_xor(a0, 32); a1 += __shfl_xor(a1, 32); a2 += __shfl_xor(a2, 32); a3 += __shfl_xor(a3, 32);
    a4 += __shfl_xor(a4, 32); a5 += __shfl_xor(a5, 32); a6 += __shfl_xor(a6, 32); a7 += __shfl_xor(a7, 32);
    // ALL lanes: self + bias + relu -> h feats (8m..8m+7)
    float dd = dinv[node];
    uint4 us = G4[node * 8 + m];
    a0 += bflo(us.x); a1 += bfhi(us.x); a2 += bflo(us.y); a3 += bfhi(us.y);
    a4 += bflo(us.z); a5 += bfhi(us.z); a6 += bflo(us.w); a7 += bfhi(us.w);
    float4 b0 = ((const float4*)b2)[2 * m];
    float4 b1v = ((const float4*)b2)[2 * m + 1];
    a0 = fmaxf(fmaf(a0, dd, b0.x), 0.f);
    a1 = fmaxf(fmaf(a1, dd, b0.y), 0.f);
    a2 = fmaxf(fmaf(a2, dd, b0.z), 0.f);
    a3 = fmaxf(fmaf(a3, dd, b0.w), 0.f);
    a4 = fmaxf(fmaf(a4, dd, b1v.x), 0.f);
    a5 = fmaxf(fmaf(a5, dd, b1v.y), 0.f);
    a6 = fmaxf(fmaf(a6, dd, b1v.z), 0.f);
    a7 = fmaxf(fmaf(a7, dd, b1v.w), 0.f);
    // FC over k in [16q,16q+16): feats of m=2q (k=16q..16q+7) and m=2q+1 (+8..15)
    int sl0 = 2 * q, sl1 = 2 * q + 1;    // e=0 lanes hold merged values
    float acc = 0.f;
    acc = fmaf(__shfl(a0, sl0), Wreg[0], acc);
    acc = fmaf(__shfl(a1, sl0), Wreg[1], acc);
    acc = fmaf(__shfl(a2, sl0), Wreg[2], acc);
    acc = fmaf(__shfl(a3, sl0), Wreg[3], acc);
    acc = fmaf(__shfl(a4, sl0), Wreg[4], acc);
    acc = fmaf(__shfl(a5, sl0), Wreg[5], acc);
    acc = fmaf(__shfl(a6, sl0), Wreg[6], acc);
    acc = fmaf(__shfl(a7, sl0), Wreg[7], acc);
    acc = fmaf(__shfl(a0, sl1), Wreg[8], acc);
    acc = fmaf(__shfl(a1, sl1), Wreg[9], acc);
    acc = fmaf(__shfl(a2, sl1), Wreg[10], acc);
    acc = fmaf(__shfl(a3, sl1), Wreg[11], acc);
    acc = fmaf(__shfl(a4, sl1), Wreg[12], acc);
    acc = fmaf(__shfl(a5, sl1), Wreg[13], acc);
    acc = fmaf(__shfl(a6, sl1), Wreg[14], acc);
    acc = fmaf(__shfl(a7, sl1), Wreg[15], acc);
    acc += __shfl_xor(acc, 16);
    acc += __shfl_xor(acc, 32);
    if (lane < 16) out[node * 16 + c] = acc + bfc[c];
}

extern "C" void kernel_launch(void* const* d_in, const int* in_sizes, int n_in,
                              void* d_out, int out_size, void* d_ws, size_t ws_size,
                              hipStream_t stream) {
    const float* x   = (const float*)d_in[0];
    const int*   ei  = (const int*)d_in[1];
    const float* W1  = (const float*)d_in[2];
    const float* b1  = (const float*)d_in[3];
    const float* W2  = (const float*)d_in[4];
    const float* b2  = (const float*)d_in[5];
    const float* Wfc = (const float*)d_in[6];
    const float* bfc = (const float*)d_in[7];
    float* out = (float*)d_out;

    const int* src = ei;
    const int* dst = ei + NE;

    // ws: bcnt[512]|brel[512] | bbase[513] | dinv[NN] | next[NN] | esrc[NE]
    //     | G[NN*32 u, 12.8MB] | bufB[NN*64 bf16, 12.8MB]   (~33 MB)
    // pairs aliases bufB (consumed by bkt_csr before gather-1 writes bufB)
    int*      bcnt  = (int*)d_ws;
    int*      brel  = bcnt + NBP;
    int*      bbase = brel + NBP;
    float*    dinv  = (float*)(bbase + NBP + 1);
    int*      next  = (int*)(dinv + NN);
    int*      esrc  = next + NN;
    unsigned* G     = (unsigned*)(esrc + NE);
    uint4*    bufB  = (uint4*)(G + (size_t)NN * 32);
    int*      pairs = (int*)bufB;

    // ---- CSR build: 4 dispatches ----
    zero_bkt<<<4, 256, 0, stream>>>(bcnt);   // zeroes bcnt + brel
    bkt_hist<<<NCHUNK, 256, 0, stream>>>(dst, bcnt);
    bkt_place<<<NCHUNK, 256, 0, stream>>>(src, dst, bcnt, brel, bbase, pairs);
    bkt_csr<<<NB, 256, 0, stream>>>(pairs, bbase, next, dinv, esrc);

    // ---- layer 1: gemm(fp32 x) -> G ; gather -> bf16 h1 ----
    gemm64g<<<NN / 16, 256, 0, stream>>>(x, W1, dinv, (ushort4*)G, NN);
    gather_bf16<<<(NN * 64) / 256, 256, 0, stream>>>(next, esrc, dinv, (const uint4*)G, b1, bufB, NN);

    // ---- layer 2: gemm(bf16 h1) -> G ; gather + FC -> out ----
    gemm64gb<<<NN / 16, 256, 0, stream>>>((const ushort4*)bufB, W2, dinv, (ushort4*)G, NN);
    gather_fc<<<NN / 4, 256, 0, stream>>>(next, esrc, dinv, (const uint4*)G, b2, Wfc, bfc, out);
}

// Round 15
// 259.537 us; speedup vs baseline: 1.2771x; 1.0877x over previous
//
#include <hip/hip_runtime.h>

#define NN 100000
#define NE 1600000
#define NB 391              // ceil(NN/256) node-buckets of 256 dst nodes
#define NBP 512             // padded bucket count
#define CHUNK 4096
#define NCHUNK 391          // ceil(NE/CHUNK)
#define CAP 5120            // bucket capacity: E[load]=4096, sigma=64 -> 16 sigma margin

static __device__ __forceinline__ unsigned short f2bf(float f) {
    unsigned u = __float_as_uint(f);
    u += 0x7fffu + ((u >> 16) & 1u);   // RNE
    return (unsigned short)(u >> 16);
}
static __device__ __forceinline__ float bflo(unsigned u) { return __uint_as_float(u << 16); }
static __device__ __forceinline__ float bfhi(unsigned u) { return __uint_as_float(u & 0xffff0000u); }

// ---------------- A0: zero bucket cursors ----------------
__global__ void zero_bkt(int* __restrict__ p) {
    int t = blockIdx.x * blockDim.x + threadIdx.x;
    if (t < NBP) p[t] = 0;
}

// ---------------- A1: placement into capacity-padded bucket regions ----------------
// No histogram pass: count chunk locally, claim region via bcur, scatter.
__global__ __launch_bounds__(256) void bkt_place(const int* __restrict__ src,
                                                 const int* __restrict__ dst,
                                                 int* __restrict__ bcur,
                                                 int* __restrict__ pairs2) {
    __shared__ int lcnt[NBP];
    __shared__ int lnext[NBP];
    int t = threadIdx.x;
    lcnt[t] = 0; lcnt[t + 256] = 0;
    __syncthreads();
    int base = blockIdx.x * CHUNK;
    int end = min(base + CHUNK, NE);
    for (int e = base + t; e < end; e += 256) atomicAdd(&lcnt[dst[e] >> 8], 1);
    __syncthreads();
    {
        int v0 = lcnt[t], v1 = lcnt[t + 256];
        lnext[t] = t * CAP + (v0 ? atomicAdd(&bcur[t], v0) : 0);
        if (v1) lnext[t + 256] = (t + 256) * CAP + atomicAdd(&bcur[t + 256], v1);
    }
    __syncthreads();
    for (int e = base + t; e < end; e += 256) {
        int d = dst[e];
        int p = atomicAdd(&lnext[d >> 8], 1);
        pairs2[p] = src[e] | ((d & 255) << 17);
    }
}

// ---------------- B: per-bucket CSR build + dinv -> next2 (start,end) ----------------
__global__ __launch_bounds__(256) void bkt_csr(const int* __restrict__ pairs2,
                                               const int* __restrict__ bcur,
                                               int2* __restrict__ next2,
                                               float* __restrict__ dinv,
                                               int* __restrict__ esrc) {
    __shared__ int cnt[256];
    __shared__ int sbuf[2][256];
    __shared__ int nxt[256];
    int b = blockIdx.x;
    int e0 = b * CAP;
    int e1 = e0 + bcur[b];
    int t = threadIdx.x;
    cnt[t] = 0;
    __syncthreads();
    for (int i = e0 + t; i < e1; i += 256) atomicAdd(&cnt[pairs2[i] >> 17], 1);
    __syncthreads();
    int v = cnt[t];
    int pi = 0; sbuf[0][t] = v; __syncthreads();
    for (int off = 1; off < 256; off <<= 1) {
        int add = (t >= off) ? sbuf[pi][t - off] : 0;
        sbuf[1 - pi][t] = sbuf[pi][t] + add;
        pi ^= 1;
        __syncthreads();
    }
    int incl = sbuf[pi][t];
    int node = b * 256 + t;
    if (node < NN) {
        next2[node] = make_int2(e0 + incl - v, e0 + incl);
        dinv[node] = rsqrtf((float)v + 1.0f);
    }
    nxt[t] = e0 + incl - v;
    __syncthreads();
    for (int i = e0 + t; i < e1; i += 256) {
        int w = pairs2[i];
        int p = atomicAdd(&nxt[w >> 17], 1);
        esrc[p] = w & 0x1FFFF;
    }
}

// ---------------- GEMM (fp32 in) [n,64]@[64,64] -> bf16 g = acc*dinv ----------------
__global__ __launch_bounds__(256) void gemm64g(const float* __restrict__ X,
                                               const float* __restrict__ W,
                                               const float* __restrict__ dinv,
                                               ushort4* __restrict__ G, int n) {
    __shared__ float4 Ws[64][16];
    __shared__ float  Xs[16][68];
    int tid = threadIdx.x;
    const float4* W4 = (const float4*)W;
    #pragma unroll
    for (int i = tid; i < 64 * 16; i += 256) Ws[i >> 4][i & 15] = W4[i];
    {
        int rr = tid >> 4, q = tid & 15;
        int node = blockIdx.x * 16 + rr;
        float4 v = ((const float4*)(X + (size_t)node * 64))[q];
        *(float4*)&Xs[rr][q * 4] = v;
    }
    __syncthreads();
    int r = tid >> 4, cq = tid & 15;
    float4 acc = {0.f, 0.f, 0.f, 0.f};
    #pragma unroll
    for (int k = 0; k < 64; ++k) {
        float x  = Xs[r][k];
        float4 w = Ws[k][cq];
        acc.x += x * w.x; acc.y += x * w.y; acc.z += x * w.z; acc.w += x * w.w;
    }
    int node = blockIdx.x * 16 + r;
    float dd = dinv[node];
    ushort4 pk;
    pk.x = f2bf(acc.x * dd); pk.y = f2bf(acc.y * dd);
    pk.z = f2bf(acc.z * dd); pk.w = f2bf(acc.w * dd);
    G[(size_t)node * 16 + cq] = pk;
}

// ---------------- GEMM (bf16 in) [n,64]@[64,64] -> bf16 g = acc*dinv ----------------
__global__ __launch_bounds__(256) void gemm64gb(const ushort4* __restrict__ X16,
                                                const float* __restrict__ W,
                                                const float* __restrict__ dinv,
                                                ushort4* __restrict__ G, int n) {
    __shared__ float4 Ws[64][16];
    __shared__ float  Xs[16][68];
    int tid = threadIdx.x;
    const float4* W4 = (const float4*)W;
    #pragma unroll
    for (int i = tid; i < 64 * 16; i += 256) Ws[i >> 4][i & 15] = W4[i];
    {
        int rr = tid >> 4, q = tid & 15;
        int node = blockIdx.x * 16 + rr;
        ushort4 u = X16[(size_t)node * 16 + q];
        float4 v;
        v.x = __uint_as_float((unsigned)u.x << 16);
        v.y = __uint_as_float((unsigned)u.y << 16);
        v.z = __uint_as_float((unsigned)u.z << 16);
        v.w = __uint_as_float((unsigned)u.w << 16);
        *(float4*)&Xs[rr][q * 4] = v;
    }
    __syncthreads();
    int r = tid >> 4, cq = tid & 15;
    float4 acc = {0.f, 0.f, 0.f, 0.f};
    #pragma unroll
    for (int k = 0; k < 64; ++k) {
        float x  = Xs[r][k];
        float4 w = Ws[k][cq];
        acc.x += x * w.x; acc.y += x * w.y; acc.z += x * w.z; acc.w += x * w.w;
    }
    int node = blockIdx.x * 16 + r;
    float dd = dinv[node];
    ushort4 pk;
    pk.x = f2bf(acc.x * dd); pk.y = f2bf(acc.y * dd);
    pk.z = f2bf(acc.z * dd); pk.w = f2bf(acc.w * dd);
    G[(size_t)node * 16 + cq] = pk;
}

// ---------------- gather-1 (uint4 lanes): agg + self + bias + relu -> bf16 h1 ----------------
__global__ __launch_bounds__(256) void gather_bf16(
        const int2* __restrict__ next2, const int* __restrict__ esrc,
        const float* __restrict__ dinv, const uint4* __restrict__ G4,
        const float* __restrict__ b, uint4* __restrict__ outH) {
    int node = (int)((blockIdx.x * blockDim.x + threadIdx.x) >> 6);
    int lane = threadIdx.x & 63;
    int e = lane >> 3, m = lane & 7;
    int2 nn = next2[node];
    int j0 = nn.x, e1 = nn.y;
    float a0 = 0.f, a1 = 0.f, a2 = 0.f, a3 = 0.f, a4 = 0.f, a5 = 0.f, a6 = 0.f, a7 = 0.f;
    int j = j0 + e;
    for (; j + 8 < e1; j += 16) {
        int s0 = esrc[j], s1 = esrc[j + 8];
        uint4 u0 = G4[s0 * 8 + m];
        uint4 u1 = G4[s1 * 8 + m];
        a0 += bflo(u0.x) + bflo(u1.x); a1 += bfhi(u0.x) + bfhi(u1.x);
        a2 += bflo(u0.y) + bflo(u1.y); a3 += bfhi(u0.y) + bfhi(u1.y);
        a4 += bflo(u0.z) + bflo(u1.z); a5 += bfhi(u0.z) + bfhi(u1.z);
        a6 += bflo(u0.w) + bflo(u1.w); a7 += bfhi(u0.w) + bfhi(u1.w);
    }
    for (; j < e1; j += 8) {
        uint4 u = G4[esrc[j] * 8 + m];
        a0 += bflo(u.x); a1 += bfhi(u.x); a2 += bflo(u.y); a3 += bfhi(u.y);
        a4 += bflo(u.z); a5 += bfhi(u.z); a6 += bflo(u.w); a7 += bfhi(u.w);
    }
    a0 += __shfl_xor(a0, 8);  a1 += __shfl_xor(a1, 8);  a2 += __shfl_xor(a2, 8);  a3 += __shfl_xor(a3, 8);
    a4 += __shfl_xor(a4, 8);  a5 += __shfl_xor(a5, 8);  a6 += __shfl_xor(a6, 8);  a7 += __shfl_xor(a7, 8);
    a0 += __shfl_xor(a0, 16); a1 += __shfl_xor(a1, 16); a2 += __shfl_xor(a2, 16); a3 += __shfl_xor(a3, 16);
    a4 += __shfl_xor(a4, 16); a5 += __shfl_xor(a5, 16); a6 += __shfl_xor(a6, 16); a7 += __shfl_xor(a7, 16);
    a0 += __shfl_xor(a0, 32); a1 += __shfl_xor(a1, 32); a2 += __shfl_xor(a2, 32); a3 += __shfl_xor(a3, 32);
    a4 += __shfl_xor(a4, 32); a5 += __shfl_xor(a5, 32); a6 += __shfl_xor(a6, 32); a7 += __shfl_xor(a7, 32);
    if (e == 0) {
        float dd = dinv[node];
        uint4 us = G4[node * 8 + m];             // self: g*dd = h*dinv^2
        a0 += bflo(us.x); a1 += bfhi(us.x); a2 += bflo(us.y); a3 += bfhi(us.y);
        a4 += bflo(us.z); a5 += bfhi(us.z); a6 += bflo(us.w); a7 += bfhi(us.w);
        float4 b0 = ((const float4*)b)[2 * m];
        float4 b1v = ((const float4*)b)[2 * m + 1];
        float h0 = fmaxf(fmaf(a0, dd, b0.x), 0.f);
        float h1 = fmaxf(fmaf(a1, dd, b0.y), 0.f);
        float h2 = fmaxf(fmaf(a2, dd, b0.z), 0.f);
        float h3 = fmaxf(fmaf(a3, dd, b0.w), 0.f);
        float h4 = fmaxf(fmaf(a4, dd, b1v.x), 0.f);
        float h5 = fmaxf(fmaf(a5, dd, b1v.y), 0.f);
        float h6 = fmaxf(fmaf(a6, dd, b1v.z), 0.f);
        float h7 = fmaxf(fmaf(a7, dd, b1v.w), 0.f);
        uint4 pk;
        pk.x = (unsigned)f2bf(h0) | ((unsigned)f2bf(h1) << 16);
        pk.y = (unsigned)f2bf(h2) | ((unsigned)f2bf(h3) << 16);
        pk.z = (unsigned)f2bf(h4) | ((unsigned)f2bf(h5) << 16);
        pk.w = (unsigned)f2bf(h6) | ((unsigned)f2bf(h7) << 16);
        outH[(size_t)node * 8 + m] = pk;
    }
}

// ---------------- gather-2 + FC fused (uint4 lanes, zero LDS/barriers) ----------------
__global__ __launch_bounds__(256) void gather_fc(
        const int2* __restrict__ next2, const int* __restrict__ esrc,
        const float* __restrict__ dinv, const uint4* __restrict__ G4,
        const float* __restrict__ b2, const float* __restrict__ Wfc,
        const float* __restrict__ bfc, float* __restrict__ out) {
    int tid = threadIdx.x;
    int w = tid >> 6, lane = tid & 63;
    int e = lane >> 3, m = lane & 7;
    int q = lane >> 4, c = lane & 15;    // FC roles
    int node = blockIdx.x * 4 + w;       // NN % 4 == 0
    float Wreg[16];
    #pragma unroll
    for (int i = 0; i < 16; ++i) Wreg[i] = Wfc[(q * 16 + i) * 16 + c];
    int2 nn = next2[node];
    int j0 = nn.x, e1 = nn.y;
    float a0 = 0.f, a1 = 0.f, a2 = 0.f, a3 = 0.f, a4 = 0.f, a5 = 0.f, a6 = 0.f, a7 = 0.f;
    int j = j0 + e;
    for (; j + 8 < e1; j += 16) {
        int s0 = esrc[j], s1 = esrc[j + 8];
        uint4 u0 = G4[s0 * 8 + m];
        uint4 u1 = G4[s1 * 8 + m];
        a0 += bflo(u0.x) + bflo(u1.x); a1 += bfhi(u0.x) + bfhi(u1.x);
        a2 += bflo(u0.y) + bflo(u1.y); a3 += bfhi(u0.y) + bfhi(u1.y);
        a4 += bflo(u0.z) + bflo(u1.z); a5 += bfhi(u0.z) + bfhi(u1.z);
        a6 += bflo(u0.w) + bflo(u1.w); a7 += bfhi(u0.w) + bfhi(u1.w);
    }
    for (; j < e1; j += 8) {
        uint4 u = G4[esrc[j] * 8 + m];
        a0 += bflo(u.x); a1 += bfhi(u.x); a2 += bflo(u.y); a3 += bfhi(u.y);
        a4 += bflo(u.z); a5 += bfhi(u.z); a6 += bflo(u.w); a7 += bfhi(u.w);
    }
    a0 += __shfl_xor(a0, 8);  a1 += __shfl_xor(a1, 8);  a2 += __shfl_xor(a2, 8);  a3 += __shfl_xor(a3, 8);
    a4 += __shfl_xor(a4, 8);  a5 += __shfl_xor(a5, 8);  a6 += __shfl_xor(a6, 8);  a7 += __shfl_xor(a7, 8);
    a0 += __shfl_xor(a0, 16); a1 += __shfl_xor(a1, 16); a2 += __shfl_xor(a2, 16); a3 += __shfl_xor(a3, 16);
    a4 += __shfl_xor(a4, 16); a5 += __shfl_xor(a5, 16); a6 += __shfl_xor(a6, 16); a7 += __shfl_xor(a7, 16);
    a0 += __shfl_xor(a0, 32); a1 += __shfl_xor(a1, 32); a2 += __shfl_xor(a2, 32); a3 += __shfl_xor(a3, 32);
    a4 += __shfl_xor(a4, 32); a5 += __shfl_xor(a5, 32); a6 += __shfl_xor(a6, 32); a7 += __shfl_xor(a7, 32);
    float dd = dinv[node];
    uint4 us = G4[node * 8 + m];
    a0 += bflo(us.x); a1 += bfhi(us.x); a2 += bflo(us.y); a3 += bfhi(us.y);
    a4 += bflo(us.z); a5 += bfhi(us.z); a6 += bflo(us.w); a7 += bfhi(us.w);
    float4 b0 = ((const float4*)b2)[2 * m];
    float4 b1v = ((const float4*)b2)[2 * m + 1];
    a0 = fmaxf(fmaf(a0, dd, b0.x), 0.f);
    a1 = fmaxf(fmaf(a1, dd, b0.y), 0.f);
    a2 = fmaxf(fmaf(a2, dd, b0.z), 0.f);
    a3 = fmaxf(fmaf(a3, dd, b0.w), 0.f);
    a4 = fmaxf(fmaf(a4, dd, b1v.x), 0.f);
    a5 = fmaxf(fmaf(a5, dd, b1v.y), 0.f);
    a6 = fmaxf(fmaf(a6, dd, b1v.z), 0.f);
    a7 = fmaxf(fmaf(a7, dd, b1v.w), 0.f);
    int sl0 = 2 * q, sl1 = 2 * q + 1;    // e=0 lanes hold merged values
    float acc = 0.f;
    acc = fmaf(__shfl(a0, sl0), Wreg[0], acc);
    acc = fmaf(__shfl(a1, sl0), Wreg[1], acc);
    acc = fmaf(__shfl(a2, sl0), Wreg[2], acc);
    acc = fmaf(__shfl(a3, sl0), Wreg[3], acc);
    acc = fmaf(__shfl(a4, sl0), Wreg[4], acc);
    acc = fmaf(__shfl(a5, sl0), Wreg[5], acc);
    acc = fmaf(__shfl(a6, sl0), Wreg[6], acc);
    acc = fmaf(__shfl(a7, sl0), Wreg[7], acc);
    acc = fmaf(__shfl(a0, sl1), Wreg[8], acc);
    acc = fmaf(__shfl(a1, sl1), Wreg[9], acc);
    acc = fmaf(__shfl(a2, sl1), Wreg[10], acc);
    acc = fmaf(__shfl(a3, sl1), Wreg[11], acc);
    acc = fmaf(__shfl(a4, sl1), Wreg[12], acc);
    acc = fmaf(__shfl(a5, sl1), Wreg[13], acc);
    acc = fmaf(__shfl(a6, sl1), Wreg[14], acc);
    acc = fmaf(__shfl(a7, sl1), Wreg[15], acc);
    acc += __shfl_xor(acc, 16);
    acc += __shfl_xor(acc, 32);
    if (lane < 16) out[node * 16 + c] = acc + bfc[c];
}

extern "C" void kernel_launch(void* const* d_in, const int* in_sizes, int n_in,
                              void* d_out, int out_size, void* d_ws, size_t ws_size,
                              hipStream_t stream) {
    const float* x   = (const float*)d_in[0];
    const int*   ei  = (const int*)d_in[1];
    const float* W1  = (const float*)d_in[2];
    const float* b1  = (const float*)d_in[3];
    const float* W2  = (const float*)d_in[4];
    const float* b2  = (const float*)d_in[5];
    const float* Wfc = (const float*)d_in[6];
    const float* bfc = (const float*)d_in[7];
    float* out = (float*)d_out;

    const int* src = ei;
    const int* dst = ei + NE;

    // ws: bcur[512] | next2[NN int2] | dinv[NN] | esrc[NB*CAP ~8MB]
    //     | G[NN*32 u, 12.8MB] | bufB[NN*64 bf16, 12.8MB]   (~35 MB)
    // pairs2 aliases bufB (consumed by bkt_csr before gather-1 writes bufB)
    int*      bcur  = (int*)d_ws;
    int2*     next2 = (int2*)(bcur + NBP);
    float*    dinv  = (float*)(next2 + NN);
    int*      esrc  = (int*)(dinv + NN);
    unsigned* G     = (unsigned*)(esrc + (size_t)NB * CAP);
    uint4*    bufB  = (uint4*)(G + (size_t)NN * 32);
    int*      pairs2 = (int*)bufB;

    // ---- CSR build: 3 dispatches (capacity-padded buckets, no hist/scan) ----
    zero_bkt<<<2, 256, 0, stream>>>(bcur);
    bkt_place<<<NCHUNK, 256, 0, stream>>>(src, dst, bcur, pairs2);
    bkt_csr<<<NB, 256, 0, stream>>>(pairs2, bcur, next2, dinv, esrc);

    // ---- layer 1: gemm(fp32 x) -> G ; gather -> bf16 h1 ----
    gemm64g<<<NN / 16, 256, 0, stream>>>(x, W1, dinv, (ushort4*)G, NN);
    gather_bf16<<<(NN * 64) / 256, 256, 0, stream>>>(next2, esrc, dinv, (const uint4*)G, b1, bufB);

    // ---- layer 2: gemm(bf16 h1) -> G ; gather + FC -> out ----
    gemm64gb<<<NN / 16, 256, 0, stream>>>((const ushort4*)bufB, W2, dinv, (ushort4*)G, NN);
    gather_fc<<<NN / 4, 256, 0, stream>>>(next2, esrc, dinv, (const uint4*)G, b2, Wfc, bfc, out);
}